// Round 6
// baseline (209.332 us; speedup 1.0000x reference)
//
#include <hip/hip_runtime.h>

typedef __attribute__((ext_vector_type(8))) short short8;
typedef __attribute__((ext_vector_type(4))) float floatx4;

#define IN_C 128
#define OUT_C 256
#define NB 32
#define HW 56
#define S_PER_N (HW * HW)          // 3136
#define M_TOTAL (NB * S_PER_N)     // 100352
#define PH 58                      // padded height
#define PW 66                      // padded width
#define XN_ELEMS (NB * PH * PW * IN_C)   // 15,679,488
#define WT_ELEMS (9 * OUT_C * IN_C)      // 294,912
#define XF_BLOCKS (PH * NB)              // 1856 transform-x blocks
#define WF_BLOCKS (WT_ELEMS / 256)       // 1152 weight blocks

__device__ __forceinline__ unsigned short f2bf(float f) {
    unsigned int u = __builtin_bit_cast(unsigned int, f);
    u = (u + 0x7FFFu + ((u >> 16) & 1u)) >> 16;   // RNE
    return (unsigned short)u;
}

// Direct global->LDS DMA, 16B per lane. LDS dest must be base + lane*16.
__device__ __forceinline__ void gld_lds16(const unsigned short* g, unsigned short* l) {
    __builtin_amdgcn_global_load_lds(
        (const __attribute__((address_space(1))) unsigned int*)g,
        (__attribute__((address_space(3))) unsigned int*)l, 16, 0, 0);
}

// Fused transform kernel, 1D grid = XF_BLOCKS + WF_BLOCKS (unchanged).
__global__ void xform_all(const float* __restrict__ x, const float* __restrict__ w,
                          unsigned short* __restrict__ xn, unsigned short* __restrict__ wt) {
    const int bid = blockIdx.x;
    const int tid = threadIdx.x;         // 256 threads

    if (bid >= XF_BLOCKS) {              // ---- weight transform ----
        const int idx = (bid - XF_BLOCKS) * 256 + tid;
        const int ic  = idx & 127;
        const int oc  = (idx >> 7) & 255;
        const int khw = idx >> 15;
        wt[idx] = f2bf(w[(oc * IN_C + ic) * 9 + khw]);
        return;
    }

    const int ihp = bid % PH;            // 0..57
    const int n   = bid / PH;            // 0..31
    unsigned int* __restrict__ row32 =
        (unsigned int*)(xn + (size_t)(n * PH + ihp) * PW * IN_C);
    const int WORDS = PW * IN_C / 2;     // 4224 uint32 per padded row

    if (ihp == 0 || ihp == PH - 1) {     // top/bottom halo rows
        for (int i = tid; i < WORDS; i += 256) row32[i] = 0u;
        return;
    }
    // left/right halo words (pix 0 and 65): 128 words
    if (tid < 128) {
        int p = (tid >> 6) * (PW - 1);   // 0 or 65
        row32[p * 64 + (tid & 63)] = 0u;
    }
    const int ih = ihp - 1;
    const float* __restrict__ xrow = x + (size_t)n * IN_C * S_PER_N + (size_t)ih * HW;
#pragma unroll
    for (int t = 0; t < 4; ++t) {
        const int item = tid + t * 256;
        if (item >= 64 * 14) break;
        const int icw  = item & 63;
        const int pix4 = item >> 6;      // 0..13 -> iw 4*pix4..+3
        const float4 v0 = *(const float4*)(xrow + (size_t)(2 * icw)     * S_PER_N + pix4 * 4);
        const float4 v1 = *(const float4*)(xrow + (size_t)(2 * icw + 1) * S_PER_N + pix4 * 4);
        unsigned int* o = row32 + (pix4 * 4 + 1) * 64 + icw;
        o[0]   = (unsigned int)f2bf(v0.x) | ((unsigned int)f2bf(v1.x) << 16);
        o[64]  = (unsigned int)f2bf(v0.y) | ((unsigned int)f2bf(v1.y) << 16);
        o[128] = (unsigned int)f2bf(v0.z) | ((unsigned int)f2bf(v1.z) << 16);
        o[192] = (unsigned int)f2bf(v0.w) | ((unsigned int)f2bf(v1.w) << 16);
    }
}

// Implicit GEMM, R3 geometry + T3 "minimum 2-phase" pipeline:
//   block 128 oc x 128 s, 4 waves, wave 64x64 (4x4 of 16x16x32 bf16 MFMA), BK=64.
//   LDS double-buffered (A[2]+B[2] = 64 KB) -> 2 blocks/CU.
//   Per K-tile t: issue 8 gld_lds for t+1 into buf[1-c]  (stage EARLY),
//                 16 ds_read_b128 + 32 MFMA on buf[c],
//                 s_waitcnt vmcnt(0)  (covered by the compute just executed),
//                 ONE s_barrier, flip. No cold drain between stage and compute.
// T21 both-sides XOR swizzle (slot u ^= row&7): 0 bank conflicts.
// T1 bijective XCD swizzle: grid 1568 = 8*196.
__global__ void __launch_bounds__(256, 2)
conv_mfma(const unsigned short* __restrict__ xn,
          const unsigned short* __restrict__ wt,
          float* __restrict__ out) {
    const int tid  = threadIdx.x;
    const int lane = tid & 63;
    const int wv   = tid >> 6;        // 0..3
    const int l15  = lane & 15;
    const int quad = lane >> 4;       // 0..3
    const int fr7  = l15 & 7;

    const int bx0 = blockIdx.x;
    const int bx  = (bx0 & 7) * 196 + (bx0 >> 3);   // XCD-contiguous remap
    const int tile_oc = bx & 1;       // 2 oc tiles of 128
    const int tile_m  = bx >> 1;      // 784 spatial tiles of 128

    const int s_blk  = tile_m * 128;
    const int oc_blk = tile_oc * 128;
    const int s0  = s_blk + (wv & 1) * 64;    // wave spatial base
    const int oc0 = oc_blk + (wv >> 1) * 64;  // wave oc base

    __shared__ unsigned short A_lds[2][128 * 64];   // [oc_local][ic64], 2x16 KB
    __shared__ unsigned short B_lds[2][128 * 64];   // [s_local][ic64],  2x16 KB

    // ---- staging addresses: thread covers (row = q*32 + tid>>3, slot = tid&7) ----
    const int srow = tid >> 3;          // 0..31 ; (q*32+srow)&7 == srow&7
    const int sic  = ((tid & 7) ^ (srow & 7)) * 8;   // T21 source-side swizzle

    const unsigned short* a_g[4];
    const unsigned short* b_g[4];
#pragma unroll
    for (int q = 0; q < 4; ++q) {
        int row = q * 32 + srow;
        a_g[q] = wt + (size_t)(oc_blk + row) * IN_C + sic;
        int sg = s_blk + row;
        int n  = sg / S_PER_N;
        int r  = sg % S_PER_N;
        int oh = r / HW, ow = r % HW;
        b_g[q] = xn + (size_t)((n * PH + oh) * PW + ow) * IN_C + sic;
    }

    // ---- fragment read offsets (elements), row stride 64, slot ^= row&7 ----
    const int slot = (quad ^ fr7) * 8;
    int afo[4], bfo[4];
#pragma unroll
    for (int i = 0; i < 4; ++i)
        afo[i] = ((wv >> 1) * 64 + i * 16 + l15) * 64 + slot;
#pragma unroll
    for (int j = 0; j < 4; ++j)
        bfo[j] = ((wv & 1) * 64 + j * 16 + l15) * 64 + slot;

    floatx4 acc[4][4];
#pragma unroll
    for (int i = 0; i < 4; ++i)
#pragma unroll
        for (int j = 0; j < 4; ++j) acc[i][j] = (floatx4){0.f, 0.f, 0.f, 0.f};

    // K-tile t (0..17): khw = t>>1, ic-half = t&1.
    //   A offset: khw*OUT_C*IN_C + (t&1)*64
    //   B offset: ((khw/3)*PW + khw%3)*IN_C + (t&1)*64
    // ---- prologue: stage tile 0 into buffer 0 ----
#pragma unroll
    for (int q = 0; q < 4; ++q) {
        gld_lds16(a_g[q], &A_lds[0][q * 2048 + tid * 8]);
        gld_lds16(b_g[q], &B_lds[0][q * 2048 + tid * 8]);
    }
    asm volatile("s_waitcnt vmcnt(0)" ::: "memory");
    __builtin_amdgcn_s_barrier();

#pragma unroll
    for (int t = 0; t < 18; ++t) {
        const int c = t & 1;                       // current buffer (compile-time)
        // -- stage tile t+1 into the other buffer, issued BEFORE compute --
        if (t < 17) {
            const int tn   = t + 1;
            const int khwn = tn >> 1;
            const int awo  = khwn * (OUT_C * IN_C) + (tn & 1) * 64;
            const int bxo  = ((khwn / 3) * PW + (khwn % 3)) * IN_C + (tn & 1) * 64;
#pragma unroll
            for (int q = 0; q < 4; ++q) {
                gld_lds16(a_g[q] + awo, &A_lds[1 - c][q * 2048 + tid * 8]);
                gld_lds16(b_g[q] + bxo, &B_lds[1 - c][q * 2048 + tid * 8]);
            }
        }
        // -- compute tile t from buf[c] --
#pragma unroll
        for (int kk = 0; kk < 2; ++kk) {
            const int ko = kk * 32;                // XOR-folded kk slot shift
            short8 a[4], b[4];
#pragma unroll
            for (int i = 0; i < 4; ++i) a[i] = *(const short8*)(&A_lds[c][0] + (afo[i] ^ ko));
#pragma unroll
            for (int j = 0; j < 4; ++j) b[j] = *(const short8*)(&B_lds[c][0] + (bfo[j] ^ ko));
#pragma unroll
            for (int i = 0; i < 4; ++i)
#pragma unroll
                for (int j = 0; j < 4; ++j)
                    acc[i][j] = __builtin_amdgcn_mfma_f32_16x16x32_bf16(
                        a[i], b[j], acc[i][j], 0, 0, 0);
        }
        // -- single wait+barrier per tile; wait covered by the compute above --
        asm volatile("s_waitcnt vmcnt(0)" ::: "memory");
        __builtin_amdgcn_s_barrier();
    }

    // Epilogue: C/D layout col=lane&15 (s), row=quad*4+reg (oc).
#pragma unroll
    for (int j = 0; j < 4; ++j) {
        int s_glob = s0 + j * 16 + l15;
        int n = s_glob / S_PER_N;
        int s = s_glob % S_PER_N;
        float* obase = out + (size_t)n * OUT_C * S_PER_N + s;
#pragma unroll
        for (int i = 0; i < 4; ++i) {
            int oc = oc0 + i * 16 + quad * 4;
#pragma unroll
            for (int r = 0; r < 4; ++r)
                obase[(size_t)(oc + r) * S_PER_N] = acc[i][j][r];
        }
    }
}

extern "C" void kernel_launch(void* const* d_in, const int* in_sizes, int n_in,
                              void* d_out, int out_size, void* d_ws, size_t ws_size,
                              hipStream_t stream) {
    const float* x = (const float*)d_in[0];
    const float* w = (const float*)d_in[1];
    float* out = (float*)d_out;

    unsigned short* xn = (unsigned short*)d_ws;      // 31,358,976 B
    unsigned short* wt = xn + XN_ELEMS;              // 589,824 B

    xform_all<<<XF_BLOCKS + WF_BLOCKS, 256, 0, stream>>>(x, w, xn, wt);
    conv_mfma<<<(M_TOTAL / 128) * 2, 256, 0, stream>>>(xn, wt, out);
}

// Round 7
// 203.344 us; speedup vs baseline: 1.0295x; 1.0295x over previous
//
#include <hip/hip_runtime.h>

typedef __attribute__((ext_vector_type(8))) short short8;
typedef __attribute__((ext_vector_type(4))) float floatx4;

#define IN_C 128
#define OUT_C 256
#define NB 32
#define HW 56
#define S_PER_N (HW * HW)          // 3136
#define M_TOTAL (NB * S_PER_N)     // 100352
#define PH 58                      // padded height
#define PW 66                      // padded width
#define XN_ELEMS (NB * PH * PW * IN_C)   // 15,679,488
#define WT_ELEMS (9 * OUT_C * IN_C)      // 294,912
#define XF_BLOCKS (PH * NB)              // 1856 transform-x blocks
#define WF_BLOCKS (WT_ELEMS / 256)       // 1152 weight blocks

__device__ __forceinline__ unsigned short f2bf(float f) {
    unsigned int u = __builtin_bit_cast(unsigned int, f);
    u = (u + 0x7FFFu + ((u >> 16) & 1u)) >> 16;   // RNE
    return (unsigned short)u;
}

// Direct global->LDS DMA, 16B per lane. LDS dest must be base + lane*16.
__device__ __forceinline__ void gld_lds16(const unsigned short* g, unsigned short* l) {
    __builtin_amdgcn_global_load_lds(
        (const __attribute__((address_space(1))) unsigned int*)g,
        (__attribute__((address_space(3))) unsigned int*)l, 16, 0, 0);
}

// Fused transform kernel, 1D grid = XF_BLOCKS + WF_BLOCKS (unchanged).
__global__ void xform_all(const float* __restrict__ x, const float* __restrict__ w,
                          unsigned short* __restrict__ xn, unsigned short* __restrict__ wt) {
    const int bid = blockIdx.x;
    const int tid = threadIdx.x;         // 256 threads

    if (bid >= XF_BLOCKS) {              // ---- weight transform ----
        const int idx = (bid - XF_BLOCKS) * 256 + tid;
        const int ic  = idx & 127;
        const int oc  = (idx >> 7) & 255;
        const int khw = idx >> 15;
        wt[idx] = f2bf(w[(oc * IN_C + ic) * 9 + khw]);
        return;
    }

    const int ihp = bid % PH;            // 0..57
    const int n   = bid / PH;            // 0..31
    unsigned int* __restrict__ row32 =
        (unsigned int*)(xn + (size_t)(n * PH + ihp) * PW * IN_C);
    const int WORDS = PW * IN_C / 2;     // 4224 uint32 per padded row

    if (ihp == 0 || ihp == PH - 1) {     // top/bottom halo rows
        for (int i = tid; i < WORDS; i += 256) row32[i] = 0u;
        return;
    }
    // left/right halo words (pix 0 and 65): 128 words
    if (tid < 128) {
        int p = (tid >> 6) * (PW - 1);   // 0 or 65
        row32[p * 64 + (tid & 63)] = 0u;
    }
    const int ih = ihp - 1;
    const float* __restrict__ xrow = x + (size_t)n * IN_C * S_PER_N + (size_t)ih * HW;
#pragma unroll
    for (int t = 0; t < 4; ++t) {
        const int item = tid + t * 256;
        if (item >= 64 * 14) break;
        const int icw  = item & 63;
        const int pix4 = item >> 6;      // 0..13 -> iw 4*pix4..+3
        const float4 v0 = *(const float4*)(xrow + (size_t)(2 * icw)     * S_PER_N + pix4 * 4);
        const float4 v1 = *(const float4*)(xrow + (size_t)(2 * icw + 1) * S_PER_N + pix4 * 4);
        unsigned int* o = row32 + (pix4 * 4 + 1) * 64 + icw;
        o[0]   = (unsigned int)f2bf(v0.x) | ((unsigned int)f2bf(v1.x) << 16);
        o[64]  = (unsigned int)f2bf(v0.y) | ((unsigned int)f2bf(v1.y) << 16);
        o[128] = (unsigned int)f2bf(v0.z) | ((unsigned int)f2bf(v1.z) << 16);
        o[192] = (unsigned int)f2bf(v0.w) | ((unsigned int)f2bf(v1.w) << 16);
    }
}

// Implicit GEMM (R3 schedule, register-dieted for 4 blocks/CU):
//   block 128 oc x 128 s, 4 waves, wave 64x64 (4x4 of 16x16x32 bf16 MFMA), BK=64,
//   2-barrier per K-step, LDS 32 KB single-buffered.
// Register diet: 32-bit offsets from uniform bases (a/b/out), fragment offsets
//   collapsed to 2 scalars (+i*1024 folded into ds_read immediates).
//   Target: VGPR<=64 + AGPR 64 = 128 total -> 4 waves/SIMD = 4 blocks/CU
//   (was 68+64=132 -> 3 blocks/CU). Occupancy is the proven lever (R2/R4/R6).
// T21 both-sides XOR swizzle (slot u ^= row&7): 0 bank conflicts.
// T1 bijective XCD swizzle: grid 1568 = 8*196.
__global__ void __launch_bounds__(256, 4)
conv_mfma(const unsigned short* __restrict__ xn,
          const unsigned short* __restrict__ wt,
          float* __restrict__ out) {
    const int tid  = threadIdx.x;
    const int lane = tid & 63;
    const int wv   = tid >> 6;        // 0..3
    const int l15  = lane & 15;
    const int quad = lane >> 4;       // 0..3
    const int fr7  = l15 & 7;

    const int bx0 = blockIdx.x;
    const int bx  = (bx0 & 7) * 196 + (bx0 >> 3);   // XCD-contiguous remap
    const int tile_oc = bx & 1;       // 2 oc tiles of 128
    const int tile_m  = bx >> 1;      // 784 spatial tiles of 128

    const int s_blk  = tile_m * 128;
    const int oc_blk = tile_oc * 128;

    __shared__ unsigned short A_lds[128 * 64];   // [oc_local][ic64] 16 KB (swizzled)
    __shared__ unsigned short B_lds[128 * 64];   // [s_local][ic64]  16 KB (swizzled)

    // ---- staging: thread covers (row = q*32 + tid>>3, slot = tid&7), 32-bit offs ----
    const int srow = tid >> 3;          // 0..31 ; (q*32+srow)&7 == srow&7
    const int sic  = ((tid & 7) ^ (srow & 7)) * 8;   // T21 source-side swizzle

    unsigned int aoff[4], boff[4];
#pragma unroll
    for (int q = 0; q < 4; ++q) {
        int row = q * 32 + srow;
        aoff[q] = (unsigned int)((oc_blk + row) * IN_C + sic);
        int sg = s_blk + row;
        int n  = sg / S_PER_N;
        int r  = sg % S_PER_N;
        int oh = r / HW, ow = r % HW;
        boff[q] = (unsigned int)(((n * PH + oh) * PW + ow) * IN_C + sic);
    }

    // ---- fragment read offsets: base + i*1024 (folded into ds_read imm) ----
    // elem(row,kk) = row*64 + ((quad^fr7)*8 ^ kk*32); row = wrow0 + i*16.
    const int slot = (quad ^ fr7) * 8;
    const int aof0 = ((wv >> 1) * 64 + l15) * 64 + slot;
    const int bof0 = ((wv & 1)  * 64 + l15) * 64 + slot;

    floatx4 acc[4][4];
#pragma unroll
    for (int i = 0; i < 4; ++i)
#pragma unroll
        for (int j = 0; j < 4; ++j) acc[i][j] = (floatx4){0.f, 0.f, 0.f, 0.f};

#pragma unroll
    for (int khw = 0; khw < 9; ++khw) {
        const int xo = ((khw / 3) * PW + (khw % 3)) * IN_C;  // activation k-offset
        const int wo = khw * OUT_C * IN_C;                   // weight k-offset
#pragma unroll
        for (int h = 0; h < 2; ++h) {
            const int ic0 = h * 64;
            __syncthreads();                      // previous tile consumed
#pragma unroll
            for (int q = 0; q < 4; ++q) {
                gld_lds16(wt + (aoff[q] + (unsigned)(wo + ic0)), A_lds + q * 2048 + tid * 8);
                gld_lds16(xn + (boff[q] + (unsigned)(xo + ic0)), B_lds + q * 2048 + tid * 8);
            }
            __syncthreads();                      // tile loaded (vmcnt drained)

#pragma unroll
            for (int kk = 0; kk < 2; ++kk) {
                const int ka = aof0 ^ (kk * 32);  // XOR hoisted: (x+i*1024)^32 == (x^32)+i*1024
                const int kb = bof0 ^ (kk * 32);
                short8 a[4], b[4];
#pragma unroll
                for (int i = 0; i < 4; ++i) a[i] = *(const short8*)(A_lds + ka + i * 1024);
#pragma unroll
                for (int j = 0; j < 4; ++j) b[j] = *(const short8*)(B_lds + kb + j * 1024);
#pragma unroll
                for (int i = 0; i < 4; ++i)
#pragma unroll
                    for (int j = 0; j < 4; ++j)
                        acc[i][j] = __builtin_amdgcn_mfma_f32_16x16x32_bf16(
                            a[i], b[j], acc[i][j], 0, 0, 0);
            }
        }
    }

    // Epilogue: C/D layout col=lane&15 (s), row=quad*4+reg (oc). 32-bit addressing.
    const int s0  = s_blk + (wv & 1) * 64;
    const int oc0 = oc_blk + (wv >> 1) * 64;
#pragma unroll
    for (int j = 0; j < 4; ++j) {
        int s_glob = s0 + j * 16 + l15;
        int n = s_glob / S_PER_N;
        int s = s_glob % S_PER_N;
        unsigned int obase = (unsigned int)(n * OUT_C * S_PER_N + s);
#pragma unroll
        for (int i = 0; i < 4; ++i) {
            unsigned int ooff = obase + (unsigned int)((oc0 + i * 16 + quad * 4) * S_PER_N);
#pragma unroll
            for (int r = 0; r < 4; ++r)
                out[ooff + (unsigned int)(r * S_PER_N)] = acc[i][j][r];
        }
    }
}

extern "C" void kernel_launch(void* const* d_in, const int* in_sizes, int n_in,
                              void* d_out, int out_size, void* d_ws, size_t ws_size,
                              hipStream_t stream) {
    const float* x = (const float*)d_in[0];
    const float* w = (const float*)d_in[1];
    float* out = (float*)d_out;

    unsigned short* xn = (unsigned short*)d_ws;      // 31,358,976 B
    unsigned short* wt = xn + XN_ELEMS;              // 589,824 B

    xform_all<<<XF_BLOCKS + WF_BLOCKS, 256, 0, stream>>>(x, w, xn, wt);
    conv_mfma<<<(M_TOTAL / 128) * 2, 256, 0, stream>>>(xn, wt, out);
}